// Round 3
// baseline (30233.566 us; speedup 1.0000x reference)
//
#include <hip/hip_runtime.h>
#include <hip/hip_cooperative_groups.h>

namespace cg = cooperative_groups;

#define B_   64
#define T_   512
#define DI_  512
#define H_   1024
#define G4H  4096

__device__ __forceinline__ float sigm(float x) {
    return 1.0f / (1.0f + __expf(-x));
}
__device__ __forceinline__ float tanh_fast(float x) {
    return 2.0f / (1.0f + __expf(-2.0f * x)) - 1.0f;
}

// Pack Whh into per-block slices: Wpk[bid][k][n] = Whh[(n>>2)*1024 + bid*4 + (n&3)][k]
// Block bid owns h-columns j0..j0+3 (j0 = bid*4) -> 16 gate rows (4 gates x 4 cols).
__global__ __launch_bounds__(256) void pack_whh(
    const float* __restrict__ Whh, float* __restrict__ Wpk)
{
    const int bid = blockIdx.x;
    const int j0  = bid * 4;
    const int tid = threadIdx.x;
    const int n   = tid >> 4;      // 0..15
    const int lo  = tid & 15;      // 0..15
    const int row = (n >> 2) * H_ + j0 + (n & 3);
    const float* src = Whh + (size_t)row * H_;
    float* dst = Wpk + (size_t)bid * 16384 + n;
#pragma unroll
    for (int u = 0; u < 16; ++u) {
        const int k = u * 64 + lo * 4;
        const float4 v = *(const float4*)(src + k);
        dst[(size_t)(k + 0) * 16] = v.x;
        dst[(size_t)(k + 1) * 16] = v.y;
        dst[(size_t)(k + 2) * 16] = v.z;
        dst[(size_t)(k + 3) * 16] = v.w;
    }
}

// xp[tl][b][n] = X[b][t0+tl][:] . Wih[n][:] + (bih[n]+bhh[n])   (unchanged)
__global__ __launch_bounds__(256) void xproj_gemm(
    const float* __restrict__ X, const float* __restrict__ Wih,
    const float* __restrict__ bih, const float* __restrict__ bhh,
    float* __restrict__ xp, int t0)
{
    __shared__ float As[16][64];   // [k][b]
    __shared__ float Bs[16][64];   // [k][n]
    const int tl = blockIdx.y;
    const int n0 = blockIdx.x * 64;
    const int t  = t0 + tl;
    const int tid = threadIdx.x;
    const int ab = tid >> 2;
    const int ak = (tid & 3) * 4;
    const int wn = tid >> 2;
    const int wk = (tid & 3) * 4;
    const int by = tid >> 4;
    const int nx = tid & 15;

    const float* Ap = X + ((size_t)ab * T_ + t) * DI_ + ak;
    const float* Bp = Wih + (size_t)(n0 + wn) * DI_ + wk;

    float acc[4][4] = {};

    for (int k0 = 0; k0 < DI_; k0 += 16) {
        const float4 av = *(const float4*)(Ap + k0);
        const float4 bv = *(const float4*)(Bp + k0);
        __syncthreads();
        As[ak + 0][ab] = av.x; As[ak + 1][ab] = av.y;
        As[ak + 2][ab] = av.z; As[ak + 3][ab] = av.w;
        Bs[wk + 0][wn] = bv.x; Bs[wk + 1][wn] = bv.y;
        Bs[wk + 2][wn] = bv.z; Bs[wk + 3][wn] = bv.w;
        __syncthreads();
#pragma unroll
        for (int k = 0; k < 16; ++k) {
            const float4 a4 = *(const float4*)&As[k][by * 4];
            const float4 b4 = *(const float4*)&Bs[k][nx * 4];
            const float ar[4] = {a4.x, a4.y, a4.z, a4.w};
            const float br[4] = {b4.x, b4.y, b4.z, b4.w};
#pragma unroll
            for (int i = 0; i < 4; ++i)
#pragma unroll
                for (int j = 0; j < 4; ++j)
                    acc[i][j] = fmaf(ar[i], br[j], acc[i][j]);
        }
    }

    const int nb = n0 + nx * 4;
    const float4 b1 = *(const float4*)(bih + nb);
    const float4 b2 = *(const float4*)(bhh + nb);
    const float4 bb4 = {b1.x + b2.x, b1.y + b2.y, b1.z + b2.z, b1.w + b2.w};
#pragma unroll
    for (int i = 0; i < 4; ++i) {
        const int b = by * 4 + i;
        float4 v;
        v.x = acc[i][0] + bb4.x;
        v.y = acc[i][1] + bb4.y;
        v.z = acc[i][2] + bb4.z;
        v.w = acc[i][3] + bb4.w;
        *(float4*)(xp + ((size_t)tl * B_ + b) * G4H + nb) = v;
    }
}

// Persistent cooperative recurrence kernel.
// 256 blocks x 512 threads. Block bid owns h-cols j0..j0+3 (16 gate rows).
// Round-3 changes: (1) 8-deep register prefetch queue for hT tiles -> one
// latency exposure per step instead of ~16 serialized misses post-L2-invalidate;
// (2) xp prefetched to regs at step start, consumed after K-loop; (3) explicit
// LDS partials reduce (no atomics); (4) hT DOUBLE-BUFFERED by t parity (fixes
// latent WAR race: h_new writes vs other blocks' reads of old h).
__global__ __launch_bounds__(512) void lstm_recur(
    const float* __restrict__ Wpk, const float* __restrict__ xp,
    float* __restrict__ hTbuf, float* __restrict__ cS,
    float* __restrict__ hs, float* __restrict__ cs,
    int t0, int clen)
{
    __shared__ float Ws[16384];        // 64 KB resident W slice [k][16n]
    __shared__ float Hs[2][4096];      // two 64k x 64b h tiles
    __shared__ float Ps[8][1056];      // per-wave partials, padded
    __shared__ float xpl[1024];        // xp slice, [n][b]
    __shared__ float cloc[256];        // [q][b] cell state
    __shared__ float hloc[256];        // [q][b] h_new staging

    const int tid = threadIdx.x;
    const int bid = blockIdx.x;
    const int j0  = bid * 4;
    const float* Wb = Wpk + (size_t)bid * 16384;

    const int wv = tid >> 6;           // wave 0..7 -> k-slice
    const int ln = tid & 63;
    const int b4 = ln >> 2;            // 0..15
    const int n4 = ln & 3;             // 0..3 (gate index)

    // one-time: W slice -> LDS; c slice -> LDS
#pragma unroll
    for (int u = 0; u < 8; ++u)
        *(float4*)&Ws[u * 2048 + tid * 4] = *(const float4*)(Wb + u * 2048 + tid * 4);
    if (tid < 256) {
        const int b = tid & 63, qq = tid >> 6;
        cloc[qq * 64 + b] = cS[(size_t)b * H_ + j0 + qq];
    }
    __syncthreads();

    cg::grid_group grid = cg::this_grid();

    for (int tl = 0; tl < clen; ++tl) {
        const int t = t0 + tl;
        const float* hrd = hTbuf + ((t & 1) ? 65536 : 0);
        float*       hwr = hTbuf + ((t & 1) ? 0 : 65536);

        // ---- prologue: issue xp prefetch, then 8-tile load queue; write tile0 ----
        float4 xpr = {0.f, 0.f, 0.f, 0.f};
        if (tid < 256) {
            const int b = tid >> 2, g = tid & 3;
            xpr = *(const float4*)(xp + ((size_t)tl * B_ + b) * G4H + g * H_ + j0);
        }
        float4 q[8][2];
#pragma unroll
        for (int p = 0; p < 8; ++p) {
            q[p][0] = *(const float4*)(hrd + p * 4096 + tid * 4);
            q[p][1] = *(const float4*)(hrd + p * 4096 + 2048 + tid * 4);
        }
        *(float4*)&Hs[0][tid * 4]        = q[0][0];
        *(float4*)&Hs[0][2048 + tid * 4] = q[0][1];
        __syncthreads();

        // ---- K loop: 16 tiles, 8-deep pipeline, fully unrolled (static q idx) ----
        float acc[4][4] = {};
#pragma unroll
        for (int kt = 0; kt < 16; ++kt) {
            if (kt < 8) {
                q[kt][0] = *(const float4*)(hrd + (kt + 8) * 4096 + tid * 4);
                q[kt][1] = *(const float4*)(hrd + (kt + 8) * 4096 + 2048 + tid * 4);
            }
            const float* Hb = &Hs[kt & 1][0];
            const float* Wk = &Ws[kt * 1024];
#pragma unroll
            for (int kk = 0; kk < 8; ++kk) {
                const int k = wv * 8 + kk;
                const float4 hv = *(const float4*)(Hb + k * 64 + b4 * 4);
                const float4 wq = *(const float4*)(Wk + k * 16 + n4 * 4);
                const float hr[4] = {hv.x, hv.y, hv.z, hv.w};
                const float wr[4] = {wq.x, wq.y, wq.z, wq.w};
#pragma unroll
                for (int i = 0; i < 4; ++i)
#pragma unroll
                    for (int j = 0; j < 4; ++j)
                        acc[i][j] = fmaf(hr[i], wr[j], acc[i][j]);
            }
            if (kt < 15) {
                const int ns = (kt + 1) & 7;
                *(float4*)&Hs[(kt + 1) & 1][tid * 4]        = q[ns][0];
                *(float4*)&Hs[(kt + 1) & 1][2048 + tid * 4] = q[ns][1];
            }
            __syncthreads();
        }

        // ---- write partials + xp slice to LDS ----
        float* Pw = &Ps[wv][0];
#pragma unroll
        for (int j = 0; j < 4; ++j)
#pragma unroll
            for (int i = 0; i < 4; ++i)
                Pw[(j * 4 + i) * 64 + n4 * 16 + b4] = acc[i][j];   // bank: 2-way, free
        if (tid < 256) {
            const int b = tid >> 2, g = tid & 3;
            xpl[(g * 4 + 0) * 64 + b] = xpr.x;
            xpl[(g * 4 + 1) * 64 + b] = xpr.y;
            xpl[(g * 4 + 2) * 64 + b] = xpr.z;
            xpl[(g * 4 + 3) * 64 + b] = xpr.w;
        }
        __syncthreads();

        // ---- reduce + pointwise: item (b, qc) over 256 threads ----
        if (tid < 256) {
            const int b = tid & 63, qc = tid >> 6;
            const int b4p = b >> 2, ip = b & 3;
            float s[4];
#pragma unroll
            for (int g = 0; g < 4; ++g) {
                float v = xpl[(g * 4 + qc) * 64 + b];
#pragma unroll
                for (int w = 0; w < 8; ++w)
                    v += Ps[w][(qc * 4 + ip) * 64 + g * 16 + b4p];
                s[g] = v;
            }
            const float c0 = cloc[qc * 64 + b];
            const float c2 = fmaf(sigm(s[1]), c0, sigm(s[0]) * tanh_fast(s[2]));
            const float hh = sigm(s[3]) * tanh_fast(c2);
            cloc[qc * 64 + b] = c2;
            hloc[qc * 64 + b] = hh;
        }
        __syncthreads();

        // ---- outputs (float4) + next-step hT write ----
        if (tid < 64) {
            const int b = tid;
            float4 h4, c4;
            h4.x = hloc[0 * 64 + b]; h4.y = hloc[1 * 64 + b];
            h4.z = hloc[2 * 64 + b]; h4.w = hloc[3 * 64 + b];
            c4.x = cloc[0 * 64 + b]; c4.y = cloc[1 * 64 + b];
            c4.z = cloc[2 * 64 + b]; c4.w = cloc[3 * 64 + b];
            const size_t o = ((size_t)b * T_ + t) * H_ + j0;
            *(float4*)(hs + o) = h4;
            *(float4*)(cs + o) = c4;
            const int qq = tid >> 4, x = tid & 15;
            *(float4*)(hwr + (j0 + qq) * 64 + x * 4) = *(const float4*)(hloc + qq * 64 + x * 4);
        }
        grid.sync();
    }

    // persist c for next chunk
    if (tid < 256) {
        const int b = tid & 63, qq = tid >> 6;
        cS[(size_t)b * H_ + j0 + qq] = cloc[qq * 64 + b];
    }
}

__global__ __launch_bounds__(256) void gather_last(
    const float* __restrict__ hs, const float* __restrict__ cs,
    const int* __restrict__ length,
    float* __restrict__ hl, float* __restrict__ cl)
{
    const int i = blockIdx.x * 256 + threadIdx.x;   // B*H total
    const int b = i >> 10;
    const int j = i & 1023;
    const int tt = length[b] - 1;
    const size_t src = ((size_t)b * T_ + tt) * H_ + j;
    hl[i] = hs[src];
    cl[i] = cs[src];
}

extern "C" void kernel_launch(void* const* d_in, const int* in_sizes, int n_in,
                              void* d_out, int out_size, void* d_ws, size_t ws_size,
                              hipStream_t stream)
{
    const float* X   = (const float*)d_in[0];
    const float* Wih = (const float*)d_in[1];
    const float* Whh = (const float*)d_in[2];
    const float* bih = (const float*)d_in[3];
    const float* bhh = (const float*)d_in[4];
    const int*   len = (const int*)d_in[5];

    float* out = (float*)d_out;
    float* hs = out;
    float* cs = hs + (size_t)B_ * T_ * H_;
    float* hl = cs + (size_t)B_ * T_ * H_;
    float* cl = hl + (size_t)B_ * H_;

    // ws layout: hTbuf (2 x 1024x64) | cS (64x1024) | Wpk (1024x4096) | xp chunk
    float* hTbuf = (float*)d_ws;
    float* cS    = hTbuf + 2 * 65536;
    float* Wpk   = cS + 65536;
    float* xp    = Wpk + (size_t)H_ * G4H;

    const size_t fixed_bytes =
        ((size_t)3 * 65536 + (size_t)H_ * G4H) * sizeof(float);
    const size_t per_t = (size_t)B_ * G4H * sizeof(float);   // 1 MiB per timestep

    int Tc = 1;
    if (ws_size > fixed_bytes + per_t) {
        size_t m = (ws_size - fixed_bytes) / per_t;
        Tc = (int)(m > (size_t)T_ ? (size_t)T_ : m);
    }

    hipMemsetAsync(hTbuf, 0, (size_t)3 * 65536 * sizeof(float), stream);  // hT both bufs + cS
    pack_whh<<<256, 256, 0, stream>>>(Whh, Wpk);

    for (int t0 = 0; t0 < T_; t0 += Tc) {
        const int clen = (T_ - t0 < Tc) ? (T_ - t0) : Tc;
        xproj_gemm<<<dim3(G4H / 64, clen), 256, 0, stream>>>(X, Wih, bih, bhh, xp, t0);
        int t0a = t0, cla = clen;
        void* args[] = {(void*)&Wpk, (void*)&xp, (void*)&hTbuf, (void*)&cS,
                        (void*)&hs, (void*)&cs, (void*)&t0a, (void*)&cla};
        hipLaunchCooperativeKernel((const void*)lstm_recur, dim3(256), dim3(512),
                                   args, 0, stream);
    }

    gather_last<<<(B_ * H_) / 256, 256, 0, stream>>>(hs, cs, len, hl, cl);
}